// Round 11
// baseline (105.657 us; speedup 1.0000x reference)
//
#include <hip/hip_runtime.h>
#include <stdint.h>

// GCN 2-layer forward, slot-CSR gather, 4 kernels:
//   zero -> (MFMA-gemm || fill, block-range split) -> gather1 -> gather2
// Math: h1 = X @ W1   [MFMA bf16 Markidis split: Xh*Wh + Xl*Wh + Xh*Wl,
//                      fp32 accum; stored bf16 UNSCALED]
//       h[i] = relu(di*(sum_s ds*h1[s] + di*h1[i]) + b1),  di = rsqrt(cnt[i]+1)
//       hs2[i] = di * (h[i] @ W2)            (fused into gather1 epilogue)
//       out[i] = di*(sum_s hs2[s] + hs2[i]) + b2
//
// Slot-CSR: cnt[n] int + slots[n][CAP] uint16 (src < 65536), one atomic pass.
// ws layout (4-byte words): cnt[n] | slots16[n*CAP/2] | hs1b[n*64] | hs2[2n]

#define D 128
#define CAP 64     // neighbor slots per node (deg ~ Poisson(12); P(>=64)~1e-24)
#define NRT 3125   // 50000 / 16 row-tiles
#define NT 4       // row-tiles per gemm block
#define GEMMB 782  // ceil(NRT/NT); gemm blocks FIRST (longest-running)

typedef short short8 __attribute__((ext_vector_type(8)));
typedef float f32x4 __attribute__((ext_vector_type(4)));

// ---- bf16 helpers ----
__device__ __forceinline__ float2 bf2_to_f2(unsigned int u) {
    float2 r;
    r.x = __uint_as_float(u << 16);
    r.y = __uint_as_float(u & 0xffff0000u);
    return r;
}
__device__ __forceinline__ unsigned short f2bf(float f) {   // RNE f32 -> bf16
    unsigned int u = __float_as_uint(f);
    return (unsigned short)((u + 0x7fffu + ((u >> 16) & 1u)) >> 16);
}
__device__ __forceinline__ float bf2f(unsigned short s) {
    return __uint_as_float(((unsigned int)s) << 16);
}

__global__ __launch_bounds__(256) void zero_kernel(int4* __restrict__ p, int n4) {
    int i = blockIdx.x * 256 + threadIdx.x;
    if (i < n4) p[i] = make_int4(0, 0, 0, 0);
}

// Blocks [0,GEMMB): MFMA gemm (long-running, dispatched first).
// Blocks [GEMMB, GEMMB+fillB): fill, ONE edge per thread (no serial chain).
__global__ __launch_bounds__(256) void fill_gemm_kernel(
    const float* __restrict__ x, const int* __restrict__ ei,
    const float* __restrict__ W1,
    int* __restrict__ cnt, unsigned short* __restrict__ slots,
    unsigned short* __restrict__ h1u,   // [n*128] bf16 (unscaled X@W1)
    int n, int E)
{
    const int tid = threadIdx.x;

    if (blockIdx.x >= GEMMB) {
        // ---- fill: slots[dst][atomicAdd(cnt[dst])] = (u16)src ----
        int e = (blockIdx.x - GEMMB) * 256 + tid;
        if (e < E) {
            int d = ei[E + e];
            int pos = atomicAdd(&cnt[d], 1);
            if (pos < CAP) slots[(size_t)d * CAP + pos] = (unsigned short)ei[e];
        }
        return;
    }

    // ---------------- MFMA gemm ----------------
    __shared__ unsigned short Ah[16 * 128];  // 4 KiB, XOR-swizzled rows
    __shared__ unsigned short Al[16 * 128];  // 4 KiB

    const int wave = tid >> 6, lane = tid & 63;
    const int ln = lane & 15;        // A-row / B-col / C-col index
    const int kg = lane >> 4;        // k-group (0..3)
    const int cb = wave * 32;        // wave's first column

    // --- W fragments: batch ALL 64 loads (in flight together), then convert ---
    float wv[2][4][8];
#pragma unroll
    for (int ct = 0; ct < 2; ++ct)
#pragma unroll
        for (int ks = 0; ks < 4; ++ks)
#pragma unroll
            for (int j = 0; j < 8; ++j)
                wv[ct][ks][j] = W1[(size_t)(ks * 32 + kg * 8 + j) * D + cb + ct * 16 + ln];

    short8 bh[2][4], bl[2][4];
#pragma unroll
    for (int ct = 0; ct < 2; ++ct)
#pragma unroll
        for (int ks = 0; ks < 4; ++ks)
#pragma unroll
            for (int j = 0; j < 8; ++j) {
                float w = wv[ct][ks][j];
                unsigned short h = f2bf(w);
                bh[ct][ks][j] = (short)h;
                bl[ct][ks][j] = (short)f2bf(w - bf2f(h));
            }

    const int rt0 = blockIdx.x * NT;
    const int srow = tid >> 4;            // staging row 0..15
    const int skb = (tid & 15) * 8;       // staging k-base
    const int soff = ((srow * 128 + skb) ^ ((srow & 7) << 3));

    if (rt0 >= NRT) return;

    // prefetch first tile into registers
    float4 pv0, pv1;
    {
        const float* xr = &x[(size_t)(rt0 * 16 + srow) * D + skb];
        pv0 = *(const float4*)xr;
        pv1 = *(const float4*)(xr + 4);
    }

    for (int it = 0; it < NT; ++it) {
        const int rt = rt0 + it;
        if (rt >= NRT) break;

        // --- convert prefetched regs -> hi/lo bf16 LDS (swizzled) ---
        {
            const float f[8] = {pv0.x, pv0.y, pv0.z, pv0.w, pv1.x, pv1.y, pv1.z, pv1.w};
            short8 h8, l8;
#pragma unroll
            for (int j = 0; j < 8; ++j) {
                unsigned short h = f2bf(f[j]);
                h8[j] = (short)h;
                l8[j] = (short)f2bf(f[j] - bf2f(h));
            }
            *(short8*)&Ah[soff] = h8;
            *(short8*)&Al[soff] = l8;
        }
        __syncthreads();

        // --- issue next tile's loads (hide HBM latency under MFMA) ---
        if (it + 1 < NT && rt + 1 < NRT) {
            const float* xr = &x[(size_t)((rt + 1) * 16 + srow) * D + skb];
            pv0 = *(const float4*)xr;
            pv1 = *(const float4*)(xr + 4);
        }

        // --- compute: 4 k-steps x (2 ds_read_b128 + 2ct x 3 MFMA) ---
        f32x4 acc[2];
#pragma unroll
        for (int ct = 0; ct < 2; ++ct) acc[ct] = (f32x4){0.f, 0.f, 0.f, 0.f};
#pragma unroll
        for (int ks = 0; ks < 4; ++ks) {
            const int aoff = ((ln * 128 + ks * 32 + kg * 8) ^ ((ln & 7) << 3));
            short8 ah = *(const short8*)&Ah[aoff];
            short8 al = *(const short8*)&Al[aoff];
#pragma unroll
            for (int ct = 0; ct < 2; ++ct) {
                acc[ct] = __builtin_amdgcn_mfma_f32_16x16x32_bf16(ah, bh[ct][ks], acc[ct], 0, 0, 0);
                acc[ct] = __builtin_amdgcn_mfma_f32_16x16x32_bf16(al, bh[ct][ks], acc[ct], 0, 0, 0);
                acc[ct] = __builtin_amdgcn_mfma_f32_16x16x32_bf16(ah, bl[ct][ks], acc[ct], 0, 0, 0);
            }
        }
        __syncthreads();   // LDS reused next iteration

        // --- epilogue: C[row = kg*4+r][col = cb+ct*16+ln] -> bf16 ---
        const int rowBase = rt * 16;
#pragma unroll
        for (int ct = 0; ct < 2; ++ct)
#pragma unroll
            for (int r = 0; r < 4; ++r) {
                int row = rowBase + kg * 4 + r;
                h1u[(size_t)row * D + cb + ct * 16 + ln] = f2bf(acc[ct][r]);
            }
    }
}

// One wave per node. Neighbor list = one coalesced 64-lane read of slots[i][:];
// per-neighbor dinv loaded lane-parallel from cnt and shuffled with the index.
__global__ __launch_bounds__(256) void gather1_kernel(const int* __restrict__ cnt,
                                                      const unsigned short* __restrict__ slots,
                                                      const unsigned int* __restrict__ hs1b,
                                                      const float* __restrict__ b1,
                                                      const float* __restrict__ W2,
                                                      float* __restrict__ hs2, int n) {
    const int wave = threadIdx.x >> 6, lane = threadIdx.x & 63;
    const int i = blockIdx.x * 4 + wave;
    if (i >= n) return;

    const int ci = cnt[i];
    const int m = min(ci, CAP);
    const float di = rsqrtf((float)ci + 1.0f);
    int idx = (lane < m) ? (int)slots[(size_t)i * CAP + lane] : 0;
    float dl = (lane < m) ? rsqrtf((float)cnt[idx] + 1.0f) : 0.f;

    float2 h = bf2_to_f2(hs1b[(size_t)i * 64 + lane]);
    float2 acc = make_float2(di * h.x, di * h.y);   // self-loop term
    int j = 0;
    for (; j + 3 < m; j += 4) {
        int s0 = __shfl(idx, j, 64);
        int s1 = __shfl(idx, j + 1, 64);
        int s2 = __shfl(idx, j + 2, 64);
        int s3 = __shfl(idx, j + 3, 64);
        float d0 = __shfl(dl, j, 64);
        float d1 = __shfl(dl, j + 1, 64);
        float d2 = __shfl(dl, j + 2, 64);
        float d3 = __shfl(dl, j + 3, 64);
        float2 v0 = bf2_to_f2(hs1b[(size_t)s0 * 64 + lane]);
        float2 v1 = bf2_to_f2(hs1b[(size_t)s1 * 64 + lane]);
        float2 v2 = bf2_to_f2(hs1b[(size_t)s2 * 64 + lane]);
        float2 v3 = bf2_to_f2(hs1b[(size_t)s3 * 64 + lane]);
        acc.x = fmaf(d0, v0.x, fmaf(d1, v1.x, fmaf(d2, v2.x, fmaf(d3, v3.x, acc.x))));
        acc.y = fmaf(d0, v0.y, fmaf(d1, v1.y, fmaf(d2, v2.y, fmaf(d3, v3.y, acc.y))));
    }
    for (; j < m; ++j) {
        int s0 = __shfl(idx, j, 64);
        float d0 = __shfl(dl, j, 64);
        float2 v0 = bf2_to_f2(hs1b[(size_t)s0 * 64 + lane]);
        acc.x = fmaf(d0, v0.x, acc.x);
        acc.y = fmaf(d0, v0.y, acc.y);
    }

    float2 b = *(const float2*)&b1[lane * 2];
    float hx = fmaxf(fmaf(di, acc.x, b.x), 0.f);
    float hy = fmaxf(fmaf(di, acc.y, b.y), 0.f);

    // p[c] = sum_k h[k]*W2[k][c]; this lane holds k = 2*lane, 2*lane+1.
    float4 w = *(const float4*)&W2[lane * 4];
    float p0 = fmaf(hx, w.x, hy * w.z);
    float p1 = fmaf(hx, w.y, hy * w.w);
#pragma unroll
    for (int off = 32; off > 0; off >>= 1) {
        p0 += __shfl_xor(p0, off, 64);
        p1 += __shfl_xor(p1, off, 64);
    }
    if (lane == 0) {
        hs2[2 * i + 0] = di * p0;
        hs2[2 * i + 1] = di * p1;
    }
}

// out[i] = di*(sum hs2[src] + hs2[i]) + b2. One thread per node.
__global__ __launch_bounds__(256) void gather2_kernel(const int* __restrict__ cnt,
                                                      const unsigned short* __restrict__ slots,
                                                      const float* __restrict__ hs2,
                                                      const float* __restrict__ b2,
                                                      float* __restrict__ out, int n) {
    int i = blockIdx.x * 256 + threadIdx.x;
    if (i >= n) return;
    int m = min(cnt[i], CAP);
    float2 a = *(const float2*)&hs2[2 * i];
    const unsigned short* sl = &slots[(size_t)i * CAP];
    for (int e = 0; e < m; ++e) {
        int s = sl[e];
        float2 v = *(const float2*)&hs2[2 * s];
        a.x += v.x;
        a.y += v.y;
    }
    float di = rsqrtf((float)m + 1.0f);
    out[2 * i + 0] = fmaf(di, a.x, b2[0]);
    out[2 * i + 1] = fmaf(di, a.y, b2[1]);
}

extern "C" void kernel_launch(void* const* d_in, const int* in_sizes, int n_in,
                              void* d_out, int out_size, void* d_ws, size_t ws_size,
                              hipStream_t stream) {
    const float* x  = (const float*)d_in[0];
    const int*   ei = (const int*)d_in[1];   // [2,E] int32
    const float* W1 = (const float*)d_in[2];
    const float* b1 = (const float*)d_in[3];
    const float* W2 = (const float*)d_in[4];
    const float* b2 = (const float*)d_in[5];

    const int n = in_sizes[0] / D;   // 50000
    const int E = in_sizes[1] / 2;   // 600000

    int* cnt              = (int*)d_ws;                                 // n
    unsigned short* slots = (unsigned short*)(cnt + n);                 // n*CAP u16
    unsigned int* hs1b    = (unsigned int*)(slots + (size_t)n * CAP);   // n*64
    float* hs2            = (float*)(hs1b + (size_t)n * 64);            // 2n
    float* out            = (float*)d_out;

    const int n4 = n / 4;            // 50000 % 4 == 0
    const int fillB = (E + 255) / 256;

    zero_kernel<<<(n4 + 255) / 256, 256, 0, stream>>>((int4*)cnt, n4);
    fill_gemm_kernel<<<GEMMB + fillB, 256, 0, stream>>>(
        x, ei, W1, cnt, slots, (unsigned short*)hs1b, n, E);
    gather1_kernel<<<(n + 3) / 4, 256, 0, stream>>>(cnt, slots, hs1b, b1, W2, hs2, n);
    gather2_kernel<<<(n + 255) / 256, 256, 0, stream>>>(cnt, slots, hs2, b2, out, n);
}

// Round 12
// 94.148 us; speedup vs baseline: 1.1222x; 1.1222x over previous
//
#include <hip/hip_runtime.h>
#include <stdint.h>

// GCN 2-layer forward, bucket-CSR gather, 4 kernels:
//   zero -> (fill || MFMA-gemm, fill blocks FIRST) -> gather1 -> gather2
// Math: h1 = X @ W1   [MFMA bf16 Markidis split: Xh*Wh + Xl*Wh + Xh*Wl,
//                      fp32 accum; stored bf16 UNSCALED]
//       h[i] = relu(di*(sum_s ds*h1[s] + di*h1[i]) + b1),  di = rsqrt(cnt[i]+1)
//       hs2[i] = di * (h[i] @ W2)            (fused into gather1 epilogue)
//       out[i] = di*(sum_s hs2[s] + hs2[i]) + b2
//
// Bucket-CSR: bucket[i] = 128B = {u32 cnt, u16 slots[60], pad}. The fill's
// atomic and its dependent slot store hit the SAME cache line (one random
// line per edge instead of two) -- the R9-R11 fill was random-line bound.
//
// ws layout (4-byte words): bucket[n*32] | h1u[n*64] | hs2[2n]

#define D 128
#define CAPB 60    // slots per bucket; P(deg>60 | Poisson(12)) ~ 1e-19
#define NRT 3125   // 50000 / 16 row-tiles
#define NT 4       // row-tiles per gemm block
#define FILLB 512  // fill blocks FIRST: all 256 CUs immediately (R9 evidence)
#define GEMMB 782  // ceil(NRT/NT)

typedef short short8 __attribute__((ext_vector_type(8)));
typedef float f32x4 __attribute__((ext_vector_type(4)));

// ---- bf16 helpers ----
__device__ __forceinline__ float2 bf2_to_f2(unsigned int u) {
    float2 r;
    r.x = __uint_as_float(u << 16);
    r.y = __uint_as_float(u & 0xffff0000u);
    return r;
}
__device__ __forceinline__ unsigned short f2bf(float f) {   // RNE f32 -> bf16
    unsigned int u = __float_as_uint(f);
    return (unsigned short)((u + 0x7fffu + ((u >> 16) & 1u)) >> 16);
}
__device__ __forceinline__ float bf2f(unsigned short s) {
    return __uint_as_float(((unsigned int)s) << 16);
}

__global__ __launch_bounds__(256) void zero_kernel(int4* __restrict__ p, int n4) {
    int i = blockIdx.x * 256 + threadIdx.x;
    if (i < n4) p[i] = make_int4(0, 0, 0, 0);
}

// Blocks [0,FILLB): fill (grid-stride, instantly fully resident).
// Blocks [FILLB, FILLB+GEMMB): MFMA gemm. Halves independent (h1 unscaled).
__global__ __launch_bounds__(256) void fill_gemm_kernel(
    const float* __restrict__ x, const int* __restrict__ ei,
    const float* __restrict__ W1,
    int* __restrict__ bucket,            // [n*32] u32: word0=cnt, u16 slots 2..61
    unsigned short* __restrict__ h1u,    // [n*128] bf16 (unscaled X@W1)
    int n, int E)
{
    const int tid = threadIdx.x;

    if (blockIdx.x < FILLB) {
        unsigned short* b16 = (unsigned short*)bucket;
        for (int e = blockIdx.x * 256 + tid; e < E; e += FILLB * 256) {
            int d = ei[E + e];
            int pos = atomicAdd(&bucket[(size_t)d * 32], 1);
            if (pos < CAPB) b16[(size_t)d * 64 + 2 + pos] = (unsigned short)ei[e];
        }
        return;
    }

    // ---------------- MFMA gemm ----------------
    __shared__ unsigned short Ah[16 * 128];  // 4 KiB, XOR-swizzled rows
    __shared__ unsigned short Al[16 * 128];  // 4 KiB

    const int wave = tid >> 6, lane = tid & 63;
    const int ln = lane & 15;        // A-row / B-col / C-col index
    const int kg = lane >> 4;        // k-group (0..3)
    const int cb = wave * 32;        // wave's first column

    // --- W fragments: batch ALL 64 loads (in flight together), then convert ---
    float wv[2][4][8];
#pragma unroll
    for (int ct = 0; ct < 2; ++ct)
#pragma unroll
        for (int ks = 0; ks < 4; ++ks)
#pragma unroll
            for (int j = 0; j < 8; ++j)
                wv[ct][ks][j] = W1[(size_t)(ks * 32 + kg * 8 + j) * D + cb + ct * 16 + ln];

    short8 bh[2][4], bl[2][4];
#pragma unroll
    for (int ct = 0; ct < 2; ++ct)
#pragma unroll
        for (int ks = 0; ks < 4; ++ks)
#pragma unroll
            for (int j = 0; j < 8; ++j) {
                float w = wv[ct][ks][j];
                unsigned short h = f2bf(w);
                bh[ct][ks][j] = (short)h;
                bl[ct][ks][j] = (short)f2bf(w - bf2f(h));
            }

    const int rt0 = (blockIdx.x - FILLB) * NT;
    const int srow = tid >> 4;            // staging row 0..15
    const int skb = (tid & 15) * 8;       // staging k-base
    const int soff = ((srow * 128 + skb) ^ ((srow & 7) << 3));

    if (rt0 >= NRT) return;

    // prefetch first tile into registers
    float4 pv0, pv1;
    {
        const float* xr = &x[(size_t)(rt0 * 16 + srow) * D + skb];
        pv0 = *(const float4*)xr;
        pv1 = *(const float4*)(xr + 4);
    }

    for (int it = 0; it < NT; ++it) {
        const int rt = rt0 + it;
        if (rt >= NRT) break;

        // --- convert prefetched regs -> hi/lo bf16 LDS (swizzled) ---
        {
            const float f[8] = {pv0.x, pv0.y, pv0.z, pv0.w, pv1.x, pv1.y, pv1.z, pv1.w};
            short8 h8, l8;
#pragma unroll
            for (int j = 0; j < 8; ++j) {
                unsigned short h = f2bf(f[j]);
                h8[j] = (short)h;
                l8[j] = (short)f2bf(f[j] - bf2f(h));
            }
            *(short8*)&Ah[soff] = h8;
            *(short8*)&Al[soff] = l8;
        }
        __syncthreads();

        // --- issue next tile's loads (hide HBM latency under MFMA) ---
        if (it + 1 < NT && rt + 1 < NRT) {
            const float* xr = &x[(size_t)((rt + 1) * 16 + srow) * D + skb];
            pv0 = *(const float4*)xr;
            pv1 = *(const float4*)(xr + 4);
        }

        // --- compute: 4 k-steps x (2 ds_read_b128 + 2ct x 3 MFMA) ---
        f32x4 acc[2];
#pragma unroll
        for (int ct = 0; ct < 2; ++ct) acc[ct] = (f32x4){0.f, 0.f, 0.f, 0.f};
#pragma unroll
        for (int ks = 0; ks < 4; ++ks) {
            const int aoff = ((ln * 128 + ks * 32 + kg * 8) ^ ((ln & 7) << 3));
            short8 ah = *(const short8*)&Ah[aoff];
            short8 al = *(const short8*)&Al[aoff];
#pragma unroll
            for (int ct = 0; ct < 2; ++ct) {
                acc[ct] = __builtin_amdgcn_mfma_f32_16x16x32_bf16(ah, bh[ct][ks], acc[ct], 0, 0, 0);
                acc[ct] = __builtin_amdgcn_mfma_f32_16x16x32_bf16(al, bh[ct][ks], acc[ct], 0, 0, 0);
                acc[ct] = __builtin_amdgcn_mfma_f32_16x16x32_bf16(ah, bl[ct][ks], acc[ct], 0, 0, 0);
            }
        }
        __syncthreads();   // LDS reused next iteration

        // --- epilogue: C[row = kg*4+r][col = cb+ct*16+ln] -> bf16 ---
        const int rowBase = rt * 16;
#pragma unroll
        for (int ct = 0; ct < 2; ++ct)
#pragma unroll
            for (int r = 0; r < 4; ++r) {
                int row = rowBase + kg * 4 + r;
                h1u[(size_t)row * D + cb + ct * 16 + ln] = f2bf(acc[ct][r]);
            }
    }
}

// One wave per node. Bucket read: lane reads word (lane&31) of the 128B
// bucket; word0 = cnt, words 1..30 hold 2 u16 neighbor ids each (<=60).
// Lane j extracts neighbor j; dinv gathered lane-parallel; shfl broadcast.
__global__ __launch_bounds__(256) void gather1_kernel(const unsigned int* __restrict__ bucket,
                                                      const unsigned int* __restrict__ hs1b,
                                                      const float* __restrict__ b1,
                                                      const float* __restrict__ W2,
                                                      float* __restrict__ hs2, int n) {
    const int wave = threadIdx.x >> 6, lane = threadIdx.x & 63;
    const int i = blockIdx.x * 4 + wave;
    if (i >= n) return;

    unsigned int word = bucket[(size_t)i * 32 + (lane & 31)];
    const int ci = (int)__shfl((int)word, 0, 64);
    const int m = min(ci, CAPB);
    const float di = rsqrtf((float)ci + 1.0f);

    // neighbor j lives in word 1+(j>>1), half j&1; lane j grabs its own
    unsigned int cw = (unsigned int)__shfl((int)word, 1 + (lane >> 1), 64);
    int idx = (lane & 1) ? (int)(cw >> 16) : (int)(cw & 0xffffu);
    bool v = (lane < m);
    int cn = v ? (int)bucket[(size_t)idx * 32] : 0;      // neighbor cnt (L2-hot)
    float dl = v ? rsqrtf((float)cn + 1.0f) : 0.f;

    float2 h = bf2_to_f2(hs1b[(size_t)i * 64 + lane]);
    float2 acc = make_float2(di * h.x, di * h.y);        // self-loop term
    int j = 0;
    for (; j + 3 < m; j += 4) {
        int s0 = __shfl(idx, j, 64);
        int s1 = __shfl(idx, j + 1, 64);
        int s2 = __shfl(idx, j + 2, 64);
        int s3 = __shfl(idx, j + 3, 64);
        float d0 = __shfl(dl, j, 64);
        float d1 = __shfl(dl, j + 1, 64);
        float d2 = __shfl(dl, j + 2, 64);
        float d3 = __shfl(dl, j + 3, 64);
        float2 v0 = bf2_to_f2(hs1b[(size_t)s0 * 64 + lane]);
        float2 v1 = bf2_to_f2(hs1b[(size_t)s1 * 64 + lane]);
        float2 v2 = bf2_to_f2(hs1b[(size_t)s2 * 64 + lane]);
        float2 v3 = bf2_to_f2(hs1b[(size_t)s3 * 64 + lane]);
        acc.x = fmaf(d0, v0.x, fmaf(d1, v1.x, fmaf(d2, v2.x, fmaf(d3, v3.x, acc.x))));
        acc.y = fmaf(d0, v0.y, fmaf(d1, v1.y, fmaf(d2, v2.y, fmaf(d3, v3.y, acc.y))));
    }
    for (; j < m; ++j) {
        int s0 = __shfl(idx, j, 64);
        float d0 = __shfl(dl, j, 64);
        float2 v0 = bf2_to_f2(hs1b[(size_t)s0 * 64 + lane]);
        acc.x = fmaf(d0, v0.x, acc.x);
        acc.y = fmaf(d0, v0.y, acc.y);
    }

    float2 b = *(const float2*)&b1[lane * 2];
    float hx = fmaxf(fmaf(di, acc.x, b.x), 0.f);
    float hy = fmaxf(fmaf(di, acc.y, b.y), 0.f);

    // p[c] = sum_k h[k]*W2[k][c]; this lane holds k = 2*lane, 2*lane+1.
    float4 w = *(const float4*)&W2[lane * 4];
    float p0 = fmaf(hx, w.x, hy * w.z);
    float p1 = fmaf(hx, w.y, hy * w.w);
#pragma unroll
    for (int off = 32; off > 0; off >>= 1) {
        p0 += __shfl_xor(p0, off, 64);
        p1 += __shfl_xor(p1, off, 64);
    }
    if (lane == 0) {
        hs2[2 * i + 0] = di * p0;
        hs2[2 * i + 1] = di * p1;
    }
}

// out[i] = di*(sum hs2[src] + hs2[i]) + b2. One thread per node.
__global__ __launch_bounds__(256) void gather2_kernel(const unsigned int* __restrict__ bucket,
                                                      const float* __restrict__ hs2,
                                                      const float* __restrict__ b2,
                                                      float* __restrict__ out, int n) {
    int i = blockIdx.x * 256 + threadIdx.x;
    if (i >= n) return;
    const int ci = (int)bucket[(size_t)i * 32];
    const int m = min(ci, CAPB);
    const unsigned short* sl = (const unsigned short*)&bucket[(size_t)i * 32];
    float2 a = *(const float2*)&hs2[2 * i];
    for (int e = 0; e < m; ++e) {
        int s = sl[2 + e];
        float2 v = *(const float2*)&hs2[2 * s];
        a.x += v.x;
        a.y += v.y;
    }
    float di = rsqrtf((float)ci + 1.0f);
    out[2 * i + 0] = fmaf(di, a.x, b2[0]);
    out[2 * i + 1] = fmaf(di, a.y, b2[1]);
}

extern "C" void kernel_launch(void* const* d_in, const int* in_sizes, int n_in,
                              void* d_out, int out_size, void* d_ws, size_t ws_size,
                              hipStream_t stream) {
    const float* x  = (const float*)d_in[0];
    const int*   ei = (const int*)d_in[1];   // [2,E] int32
    const float* W1 = (const float*)d_in[2];
    const float* b1 = (const float*)d_in[3];
    const float* W2 = (const float*)d_in[4];
    const float* b2 = (const float*)d_in[5];

    const int n = in_sizes[0] / D;   // 50000
    const int E = in_sizes[1] / 2;   // 600000

    int* bucket        = (int*)d_ws;                               // n*32 u32
    unsigned int* hs1b = (unsigned int*)(bucket + (size_t)n * 32); // n*64 (= n*128 u16)
    float* hs2         = (float*)(hs1b + (size_t)n * 64);          // 2n
    float* out         = (float*)d_out;

    const int n4 = n * 8;            // bucket words / 4 = n*32/4 int4s

    zero_kernel<<<(n4 + 255) / 256, 256, 0, stream>>>((int4*)bucket, n4);
    fill_gemm_kernel<<<FILLB + GEMMB, 256, 0, stream>>>(
        x, ei, W1, bucket, (unsigned short*)hs1b, n, E);
    gather1_kernel<<<(n + 3) / 4, 256, 0, stream>>>(
        (const unsigned int*)bucket, hs1b, b1, W2, hs2, n);
    gather2_kernel<<<(n + 255) / 256, 256, 0, stream>>>(
        (const unsigned int*)bucket, hs2, b2, out, n);
}